// Round 10
// baseline (29.635 us; speedup 1.0000x reference)
//
#include <hip/hip_runtime.h>

#define H 512
#define W 512

typedef float f32x2 __attribute__((ext_vector_type(2)));
typedef float f32x4 __attribute__((ext_vector_type(4)));

// DPP wave rotates: *_ror moves data toward HIGHER lanes (dst[i]=src[i-1]).
__device__ __forceinline__ float dpp_left1(float v) {   // dst[i] = src[(i-1) & 63]
    return __int_as_float(__builtin_amdgcn_update_dpp(
        0, __float_as_int(v), 0x13C /*wave_ror:1*/, 0xF, 0xF, false));
}
__device__ __forceinline__ float dpp_right1(float v) {  // dst[i] = src[(i+1) & 63]
    return __int_as_float(__builtin_amdgcn_update_dpp(
        0, __float_as_int(v), 0x134 /*wave_rol:1*/, 0xF, 0xF, false));
}

// R6 structure (4 output rows/wave, 6144 waves) + packed-f32 column-pair math
// (v_pk_add_f32 / v_pk_fma_f32 halve VALU issue for acc/update) + 2-ahead tail loads.
__global__ __launch_bounds__(256, 4) void lvar_kernel(const float* __restrict__ x,
                                                      float* __restrict__ out) {
    const int lane = threadIdx.x;                 // 0..63, owns cols 8*lane..8*lane+7
    const int wv   = threadIdx.y;                 // 0..3
    const int bid  = blockIdx.x;
    const int wg   = (bid & 7) * 192 + (bid >> 3);// XCD-bijective (1536 % 8 == 0)
    const int img  = wg >> 5;                     // 0..47
    const int band = wg & 31;
    const int R    = band * 16 + wv * 4;          // this wave's first output row

    const float* __restrict__ xim = x + (size_t)img * (H * W);
    float* __restrict__ oim = out + (size_t)img * (H * W);
    const int c8 = lane * 8;
    const float inv2401 = 1.0f / 2401.0f;         // 1/49^2

    f32x2 s2[4], q2[4];                           // running 7-row sums, col-pair packed
    #pragma unroll
    for (int j = 0; j < 4; ++j) { s2[j] = (f32x2)0.f; q2[j] = (f32x2)0.f; }

    auto loadrow = [&](int r, f32x2 v[4]) {
        const int gr = r & (H - 1);
        const f32x4* p = (const f32x4*)(xim + gr * W + c8);
        const f32x4 a = p[0], b = p[1];
        v[0] = f32x2{a.x, a.y}; v[1] = f32x2{a.z, a.w};
        v[2] = f32x2{b.x, b.y}; v[3] = f32x2{b.z, b.w};
    };

    auto acc = [&](const f32x2 v[4]) {            // v_pk_add + v_pk_fma per pair
        #pragma unroll
        for (int j = 0; j < 4; ++j) {
            s2[j] += v[j];
            q2[j] += v[j] * v[j];                 // contract -> v_pk_fma_f32
        }
    };
    auto update = [&](const f32x2 nv[4], const f32x2 old[4]) {
        #pragma unroll
        for (int j = 0; j < 4; ++j) {
            s2[j] += nv[j] - old[j];
            q2[j] = (q2[j] + nv[j] * nv[j]) - old[j] * old[j];  // 2x v_pk_fma
        }
    };

    auto emit = [&](int r) {
        // scalar views of packed cols (compile-time indices -> direct VGPR refs)
        float Wn[14], W2[14];
        #pragma unroll
        for (int c = 0; c < 8; ++c) { Wn[3 + c] = s2[c >> 1][c & 1]; W2[3 + c] = q2[c >> 1][c & 1]; }
        #pragma unroll
        for (int t = 0; t < 3; ++t) {             // circular col halo via DPP
            Wn[t]      = dpp_left1(Wn[8 + t]);    // left neighbor's cols 5..7
            W2[t]      = dpp_left1(W2[8 + t]);
            Wn[11 + t] = dpp_right1(Wn[3 + t]);   // right neighbor's cols 0..2
            W2[11 + t] = dpp_right1(W2[3 + t]);
        }

        float res[8];
        float hs = Wn[0]+Wn[1]+Wn[2]+Wn[3]+Wn[4]+Wn[5]+Wn[6];
        float hq = W2[0]+W2[1]+W2[2]+W2[3]+W2[4]+W2[5]+W2[6];
        // var = (49*hq - hs*hs) / 49^2  (3 scalar ops/output)
        res[0] = fmaf(49.f, hq, -(hs * hs)) * inv2401;
        #pragma unroll
        for (int k = 1; k < 8; ++k) {
            hs += Wn[k + 6] - Wn[k - 1];
            hq += W2[k + 6] - W2[k - 1];
            res[k] = fmaf(49.f, hq, -(hs * hs)) * inv2401;
        }
        f32x4* qp = (f32x4*)(oim + r * W + c8);
        f32x4 o0 = {res[0], res[1], res[2], res[3]};
        f32x4 o1 = {res[4], res[5], res[6], res[7]};
        __builtin_nontemporal_store(o0, qp);      // write-once output
        __builtin_nontemporal_store(o1, qp + 1);
    };

    // ---- init: rows R-3..R-1 kept for subtraction; R..R+3 add-only ----
    f32x2 k0[4], k1[4], k2[4];
    loadrow(R - 3, k0); loadrow(R - 2, k1); loadrow(R - 1, k2);
    acc(k0); acc(k1); acc(k2);
    {
        f32x2 t[4];
        #pragma unroll
        for (int k = 0; k < 4; ++k) { loadrow(R + k, t); acc(t); }
    }

    // ---- 4 output rows; tail loads issued 2 emits ahead ----
    f32x2 va[4], vb[4], vc[4];
    loadrow(R + 4, va);
    loadrow(R + 5, vb);
    emit(R);
    loadrow(R + 6, vc);
    update(va, k0); emit(R + 1);
    update(vb, k1); emit(R + 2);
    update(vc, k2); emit(R + 3);
}

extern "C" void kernel_launch(void* const* d_in, const int* in_sizes, int n_in,
                              void* d_out, int out_size, void* d_ws, size_t ws_size,
                              hipStream_t stream) {
    const float* x = (const float*)d_in[0];
    float* out = (float*)d_out;
    const int nimg = in_sizes[0] / (H * W);       // 48
    dim3 grid(nimg * 32);                         // 1536 blocks (8 | 1536)
    dim3 block(64, 4);
    lvar_kernel<<<grid, block, 0, stream>>>(x, out);
}

// Round 11
// 25.368 us; speedup vs baseline: 1.1682x; 1.1682x over previous
//
#include <hip/hip_runtime.h>

#define H 512
#define W 512

typedef float f32x4 __attribute__((ext_vector_type(4)));

// DPP wave rotates: *_ror moves data toward HIGHER lanes (dst[i]=src[i-1]).
__device__ __forceinline__ float dpp_left1(float v) {   // dst[i] = src[(i-1) & 63]
    return __int_as_float(__builtin_amdgcn_update_dpp(
        0, __float_as_int(v), 0x13C /*wave_ror:1*/, 0xF, 0xF, false));
}
__device__ __forceinline__ float dpp_right1(float v) {  // dst[i] = src[(i+1) & 63]
    return __int_as_float(__builtin_amdgcn_update_dpp(
        0, __float_as_int(v), 0x134 /*wave_rol:1*/, 0xF, 0xF, false));
}

// R6 structure (4 output rows/wave, scalar math, DPP halo, NT stores), but the
// 3 subtract-rows are RELOADED from L2 one emit ahead instead of held in
// keep[3][8] -- frees 24 VGPRs to fit the 85-VGPR / 6-waves-per-SIMD tier.
__global__ __launch_bounds__(256, 6) void lvar_kernel(const float* __restrict__ x,
                                                      float* __restrict__ out) {
    const int lane = threadIdx.x;                 // 0..63, owns cols 8*lane..8*lane+7
    const int wv   = threadIdx.y;                 // 0..3
    const int bid  = blockIdx.x;
    const int wg   = (bid & 7) * 192 + (bid >> 3);// XCD-bijective (1536 % 8 == 0)
    const int img  = wg >> 5;                     // 0..47
    const int band = wg & 31;
    const int R    = band * 16 + wv * 4;          // this wave's first output row

    const float* __restrict__ xim = x + (size_t)img * (H * W);
    float* __restrict__ oim = out + (size_t)img * (H * W);
    const int c8 = lane * 8;
    const float inv = 1.0f / 49.0f;

    float s[8], q[8];                             // running 7-row vertical sums
    #pragma unroll
    for (int c = 0; c < 8; ++c) { s[c] = 0.f; q[c] = 0.f; }

    auto loadrow = [&](int r, float v[8]) {
        const int gr = r & (H - 1);
        const f32x4* p = (const f32x4*)(xim + gr * W + c8);
        const f32x4 a = p[0], b = p[1];
        v[0]=a.x; v[1]=a.y; v[2]=a.z; v[3]=a.w;
        v[4]=b.x; v[5]=b.y; v[6]=b.z; v[7]=b.w;
    };

    auto acc = [&](const float v[8]) {
        #pragma unroll
        for (int c = 0; c < 8; ++c) {
            s[c] += v[c];
            q[c] = fmaf(v[c], v[c], q[c]);
        }
    };
    auto update = [&](const float nv[8], const float old[8]) {
        #pragma unroll
        for (int c = 0; c < 8; ++c) {
            s[c] += nv[c] - old[c];
            q[c] = fmaf(nv[c], nv[c], q[c]);
            q[c] = fmaf(-old[c], old[c], q[c]);
        }
    };

    auto emit = [&](int r) {
        float Wn[14], W2[14];
        #pragma unroll
        for (int t = 0; t < 3; ++t) {             // circular col halo via DPP
            Wn[t]      = dpp_left1(s[5 + t]);     // left neighbor's cols 5..7
            W2[t]      = dpp_left1(q[5 + t]);
            Wn[11 + t] = dpp_right1(s[t]);        // right neighbor's cols 0..2
            W2[11 + t] = dpp_right1(q[t]);
        }
        #pragma unroll
        for (int c = 0; c < 8; ++c) { Wn[3 + c] = s[c]; W2[3 + c] = q[c]; }

        float res[8];
        float hs = Wn[0]+Wn[1]+Wn[2]+Wn[3]+Wn[4]+Wn[5]+Wn[6];
        float hq = W2[0]+W2[1]+W2[2]+W2[3]+W2[4]+W2[5]+W2[6];
        { const float m = hs * inv; res[0] = fmaf(-m, m, hq * inv); }
        #pragma unroll
        for (int k = 1; k < 8; ++k) {
            hs += Wn[k + 6] - Wn[k - 1];
            hq += W2[k + 6] - W2[k - 1];
            const float m = hs * inv;
            res[k] = fmaf(-m, m, hq * inv);
        }
        f32x4* qp = (f32x4*)(oim + r * W + c8);
        f32x4 o0 = {res[0], res[1], res[2], res[3]};
        f32x4 o1 = {res[4], res[5], res[6], res[7]};
        __builtin_nontemporal_store(o0, qp);      // write-once output
        __builtin_nontemporal_store(o1, qp + 1);
    };

    // ---- init: rows R-3 .. R+3 accumulated; nothing kept ----
    {
        float t[8];
        #pragma unroll
        for (int k = 0; k < 7; ++k) { loadrow(R - 3 + k, t); acc(t); }
    }

    // ---- 4 output rows; new-row AND old-row(L2-hot reload) one emit ahead ----
    float an[8], ao[8], bn[8], bo[8];
    loadrow(R + 4, an); loadrow(R - 3, ao);       // old rows re-fetched (L2 hit)
    emit(R);
    loadrow(R + 5, bn); loadrow(R - 2, bo);
    update(an, ao); emit(R + 1);
    loadrow(R + 6, an); loadrow(R - 1, ao);
    update(bn, bo); emit(R + 2);
    update(an, ao); emit(R + 3);
}

extern "C" void kernel_launch(void* const* d_in, const int* in_sizes, int n_in,
                              void* d_out, int out_size, void* d_ws, size_t ws_size,
                              hipStream_t stream) {
    const float* x = (const float*)d_in[0];
    float* out = (float*)d_out;
    const int nimg = in_sizes[0] / (H * W);       // 48
    dim3 grid(nimg * 32);                         // 1536 blocks (8 | 1536), 6 blocks/CU
    dim3 block(64, 4);
    lvar_kernel<<<grid, block, 0, stream>>>(x, out);
}